// Round 15
// baseline (219.621 us; speedup 1.0000x reference)
//
#include <hip/hip_runtime.h>

typedef float  f32x4  __attribute__((ext_vector_type(4)));
typedef float  f4v    __attribute__((ext_vector_type(4)));
typedef __bf16 bf16x8 __attribute__((ext_vector_type(8)));
typedef __bf16 bf16x4 __attribute__((ext_vector_type(4)));
typedef unsigned short ushort_t;

#define AS1 __attribute__((address_space(1)))
#define AS3 __attribute__((address_space(3)))

static __device__ __forceinline__ void gload_lds16(const void* g, void* l) {
  __builtin_amdgcn_global_load_lds((const AS1 void*)g, (AS3 void*)l, 16, 0, 0);
}

// mish(x) = x * u/(u+2), u = t*(t+2), t = e^x; guard large x.
static __device__ __forceinline__ float mishf(float x) {
  float t = __expf(x);
  float u = t * (t + 2.f);
  float y = x * __fdividef(u, u + 2.f);
  return (x > 15.f) ? x : y;
}

// ---------------- weight pack: fp32 -> bf16 in MFMA-fragment order --------
// idx = ((((cb*KC + c)*8 + u)*2 + n)*64 + l)*8 holds
// W[cb*32 + n*16 + (l&15)][c*256 + u*32 + (l>>4)*8 .. +8].
__global__ __launch_bounds__(256) void packw(
    const float* __restrict__ Wq, const float* __restrict__ Wk,
    const float* __restrict__ Wv, const float* __restrict__ Wp,
    const float* __restrict__ W1, const float* __restrict__ W2,
    __bf16* __restrict__ out)
{
  const int t = blockIdx.x * 256 + threadIdx.x;   // 98304 threads
  const int e0 = t * 8;
  int rel, K; const float* src;
  if      (e0 < 196608) { rel = e0;          K = 256;  src = nullptr; }
  else if (e0 < 262144) { rel = e0 - 196608; K = 256;  src = Wp; }
  else if (e0 < 524288) { rel = e0 - 262144; K = 256;  src = W1; }
  else                  { rel = e0 - 524288; K = 1024; src = W2; }
  const int percb = (K >> 8) * 8192;
  const int cb = rel / percb;  const int r1 = rel % percb;
  const int c  = r1 / 8192;    const int r2 = r1 % 8192;
  const int u  = r2 / 1024;    const int r3 = r2 % 1024;
  const int n  = r3 / 512;     const int l  = (r3 % 512) >> 3;
  const int col = cb * 32 + n * 16 + (l & 15);
  const int k   = c * 256 + u * 32 + ((l >> 4) << 3);
  const float* sp;
  if (e0 < 196608) {
    const float* qkvsrc = (col < 256) ? Wq : (col < 512 ? Wk : Wv);
    sp = qkvsrc + (size_t)(col & 255) * 256 + k;
  } else {
    sp = src + (size_t)col * K + k;
  }
  const f4v a = *(const f4v*)(sp);
  const f4v b = *(const f4v*)(sp + 4);
  bf16x8 o;
  #pragma unroll
  for (int j = 0; j < 4; ++j) { o[j] = (__bf16)a[j]; o[4 + j] = (__bf16)b[j]; }
  *(bf16x8*)(out + e0) = o;
}

__global__ void packb(const float* __restrict__ a, const float* __restrict__ b,
                      const float* __restrict__ c, float* __restrict__ o) {
  int i = threadIdx.x;  // 768 threads
  o[i] = (i < 256) ? a[i] : (i < 512 ? b[i - 256] : c[i - 512]);
}

// ---------------- LayerNorm row kernel: fp32 in -> bf16 out ----------------
__global__ __launch_bounds__(256) void ln_rows(
    const float* __restrict__ X, const float* __restrict__ g,
    const float* __restrict__ b, __bf16* __restrict__ Y)
{
  const int l = threadIdx.x & 63;
  const size_t row = (size_t)blockIdx.x * 4 + (threadIdx.x >> 6);
  const f4v x = *(const f4v*)(X + row * 256 + l * 4);
  float s = x[0] + x[1] + x[2] + x[3];
  float q = x[0]*x[0] + x[1]*x[1] + x[2]*x[2] + x[3]*x[3];
  #pragma unroll
  for (int d = 1; d < 64; d <<= 1) { s += __shfl_xor(s, d); q += __shfl_xor(q, d); }
  const float mu = s * (1.f / 256.f);
  const float rs = rsqrtf(q * (1.f / 256.f) - mu * mu + 1e-5f);
  const f4v gv = *(const f4v*)(g + l * 4);
  const f4v bv = *(const f4v*)(b + l * 4);
  bf16x4 o;
  #pragma unroll
  for (int j = 0; j < 4; ++j) o[j] = (__bf16)((x[j] - mu) * rs * gv[j] + bv[j]);
  *(bf16x4*)(Y + row * 256 + l * 4) = o;
}

// ---------------- B-streamed GEMM (occupancy-first, K<=1024) --------------
// out[M=32768][ldo](+nt*256) = act(A @ W^T + bias) (+res). K = KC*256.
// Block 512 thr / 8 waves; tile BM x 256; wave owns BM x 32. B fragments
// STREAMED per-u from the packed layout (2 live regs instead of 16): frees
// ~48 VGPR under the (512,2) 128-cap so the 8 af ds_reads pipeline instead
// of serializing at LDS latency. A staged in LDS (XOR-swizzled).
template<int BM, int NT, int KC, int ACT, int RES, int OUTBF>
__global__ __launch_bounds__(512, 2) void bgemm(
    const __bf16* __restrict__ A, const __bf16* __restrict__ Wg,
    const float* __restrict__ bias, const float* __restrict__ res,
    void* __restrict__ out, int ldo)
{
  constexpr int K  = KC * 256;
  constexpr int MR = BM / 16;              // m-frags per wave
  __shared__ __bf16 Ab[BM * 256];
  const int tid = threadIdx.x, l = tid & 63, w = tid >> 6;
  constexpr int nwg = (32768 / BM) * NT;
  const int wg = (blockIdx.x & 7) * (nwg / 8) + (blockIdx.x >> 3);
  const int mt = wg / NT, nt = wg % NT;
  const int row0 = mt * BM;
  const int col0 = nt * 256 + w * 32;
  const int cb = nt * 8 + w;               // global 32-col block index

  auto stageA = [&](int c) {
    #pragma unroll
    for (int j = 0; j < BM / 16; ++j) {
      const int s = j * 512 + tid;         // 16B unit index
      const int r = s >> 5, q = s & 31;
      gload_lds16(A + (size_t)(row0 + r) * K + c * 256 + ((q ^ (r & 7)) << 3),
                  &Ab[s << 3]);
    }
  };

  auto ldBu = [&](bf16x8* d, int c, int u) {
    const __bf16* wp = Wg + (size_t)(cb * KC + c) * 8192 + (((u << 1) * 64 + l) << 3);
    d[0] = *(const bf16x8*)(wp);
    d[1] = *(const bf16x8*)(wp + 512);
  };

  f32x4 acc[MR][2] = {};

  stageA(0);
  asm volatile("s_waitcnt vmcnt(0)" ::: "memory");
  __builtin_amdgcn_s_barrier();

  for (int c = 0;;) {
    bf16x8 b0[2], b1[2];
    ldBu(b0, c, 0);
    #pragma unroll
    for (int u = 0; u < 8; ++u) {
      if (u + 1 < 8) ldBu((u & 1) ? b0 : b1, c, u + 1);
      const bf16x8* bu = (u & 1) ? b1 : b0;
      bf16x8 af[MR];
      #pragma unroll
      for (int m = 0; m < MR; ++m) {
        const int r = m * 16 + (l & 15);
        const int q = ((u << 2) | (l >> 4)) ^ (r & 7);
        af[m] = *(const bf16x8*)&Ab[((r << 5) | q) << 3];
      }
      #pragma unroll
      for (int m = 0; m < MR; ++m) {
        acc[m][0] = __builtin_amdgcn_mfma_f32_16x16x32_bf16(af[m], bu[0], acc[m][0], 0, 0, 0);
        acc[m][1] = __builtin_amdgcn_mfma_f32_16x16x32_bf16(af[m], bu[1], acc[m][1], 0, 0, 0);
      }
    }
    if (++c == KC) break;
    __syncthreads();           // all waves done reading Ab
    stageA(c);
    asm volatile("s_waitcnt vmcnt(0)" ::: "memory");
    __builtin_amdgcn_s_barrier();
  }

  // epilogue: row-contiguous direct stores
  const float b0s = bias[col0 + (l & 15)];
  const float b1s = bias[col0 + 16 + (l & 15)];
  #pragma unroll
  for (int m = 0; m < MR; ++m) {
    #pragma unroll
    for (int r = 0; r < 4; ++r) {
      const int row = row0 + m * 16 + ((l >> 4) << 2) + r;
      float v0 = acc[m][0][r] + b0s;
      float v1 = acc[m][1][r] + b1s;
      if (ACT) { v0 = mishf(v0); v1 = mishf(v1); }
      if (OUTBF) {
        __bf16* op = (__bf16*)out + (size_t)row * ldo + col0;
        op[l & 15]        = (__bf16)v0;
        op[16 + (l & 15)] = (__bf16)v1;
      } else {
        if (RES) {
          const float* rp = res + (size_t)row * ldo + col0;
          v0 += rp[l & 15];
          v1 += rp[16 + (l & 15)];
        }
        float* op = (float*)out + (size_t)row * ldo + col0;
        op[l & 15]        = v0;
        op[16 + (l & 15)] = v1;
      }
    }
  }
}

// ---------------- split-KV flash attention over packed QKV [M][768] -------
// grid 256 = 128 q-blocks x 2 KV-halves; block 512 thr / 8 waves; wave owns
// 32 q-rows (halved per-CU LDS tile-read traffic vs 16q/wave). KEY FIX vs
// R11: __launch_bounds__(512,1) -> 256-VGPR cap; acc[2][16]+qf[2][8] (~230
// regs) fits WITHOUT scratch spills (R11's (512,2) capped at 128 and
// spilled the accumulator every iteration). Max-free softmax => partials
// additive: unnormalized partial O + partial denom; attn_merge combines.
__global__ __launch_bounds__(512, 1) void attn_split(
    const __bf16* __restrict__ QKV, __bf16* __restrict__ pO,
    float* __restrict__ pD)
{
  __shared__ __bf16 Ks[2][32][256];   // 32 KB
  __shared__ __bf16 Vs[2][256][34];   // 34 KB
  __shared__ __bf16 Ps[8][32][34];    // 17.4 KB
  const int tid = threadIdx.x, l = tid & 63, w = tid >> 6;
  const int wgs = (blockIdx.x & 7) * 32 + (blockIdx.x >> 3);
  const int half = wgs & 1, qblk = wgs >> 1;
  const int bh = qblk >> 2, qt = qblk & 3;
  const size_t rbase = (size_t)bh * 1024 * 768;
  const int qr0 = qt * 256 + w * 32;     // within bh
  const int kv0 = half * 512;

  bf16x8 qf[2][8];
  #pragma unroll
  for (int qs = 0; qs < 2; ++qs) {
    const __bf16* qp = QKV + rbase + (size_t)(qr0 + qs * 16 + (l & 15)) * 768 + ((l >> 4) << 3);
    #pragma unroll
    for (int s = 0; s < 8; ++s) qf[qs][s] = *(const bf16x8*)(qp + s * 32);
  }
  f32x4 acc[2][16] = {};
  float lacc[2][4] = {};

  const int vp = tid & 15, vc = tid >> 4;          // V: kv-pair, e-chunk
  const __bf16* gV = QKV + 512 + rbase + vc * 8;

  uint4 rv0, rv1;
  auto ldV = [&](int j) {
    const __bf16* v0 = gV + (size_t)(kv0 + j * 32 + vp * 2) * 768;
    rv0 = *(const uint4*)v0;
    rv1 = *(const uint4*)(v0 + 768);
  };
  auto stK = [&](int j, int buf) {
    #pragma unroll
    for (int i = 0; i < 2; ++i) {
      const int s = i * 512 + tid, r = s >> 5, kec = s & 31;
      gload_lds16(QKV + 256 + rbase + (size_t)(kv0 + j * 32 + r) * 768
                      + ((kec ^ (r & 15)) << 3),
                  &Ks[buf][r][kec * 8]);
    }
  };
  auto wrV = [&](int buf) {
    const ushort_t* s0 = (const ushort_t*)&rv0;
    const ushort_t* s1 = (const ushort_t*)&rv1;
    #pragma unroll
    for (int i = 0; i < 8; ++i) {
      unsigned pk = (unsigned)s0[i] | ((unsigned)s1[i] << 16);
      *(unsigned*)&Vs[buf][vc * 8 + i][vp * 2] = pk;
    }
  };

  stK(0, 0); ldV(0); wrV(0);
  __syncthreads();
  int cur = 0;
  for (int j = 0;;) {
    if (j + 1 < 16) { stK(j + 1, cur ^ 1); ldV(j + 1); }
    f32x4 S[2][2] = {};
    const char* kbase = (const char*)&Ks[cur][0][0];
    __builtin_amdgcn_s_setprio(1);
    #pragma unroll
    for (int t = 0; t < 2; ++t) {
      const int kcol = t * 16 + (l & 15);
      const int swz = (kcol & 15) << 4;
      #pragma unroll
      for (int s = 0; s < 8; ++s) {
        uint4 kf = *(const uint4*)(kbase + ((kcol * 512 + s * 64 + ((l >> 4) << 4)) ^ swz));
        const bf16x8 kb = __builtin_bit_cast(bf16x8, kf);
        S[0][t] = __builtin_amdgcn_mfma_f32_16x16x32_bf16(qf[0][s], kb, S[0][t], 0, 0, 0);
        S[1][t] = __builtin_amdgcn_mfma_f32_16x16x32_bf16(qf[1][s], kb, S[1][t], 0, 0, 0);
      }
    }
    __builtin_amdgcn_s_setprio(0);
    #pragma unroll
    for (int qs = 0; qs < 2; ++qs)
      #pragma unroll
      for (int t = 0; t < 2; ++t)
        #pragma unroll
        for (int r = 0; r < 4; ++r) {
          float p = __expf(S[qs][t][r]);
          lacc[qs][r] += p;
          Ps[w][qs * 16 + ((l >> 4) << 2) + r][t * 16 + (l & 15)] = (__bf16)p;
        }
    bf16x8 pf0 = *(const bf16x8*)&Ps[w][l & 15][(l >> 4) << 3];
    bf16x8 pf1 = *(const bf16x8*)&Ps[w][16 + (l & 15)][(l >> 4) << 3];
    __builtin_amdgcn_s_setprio(1);
    #pragma unroll
    for (int n = 0; n < 16; ++n) {
      uint4 vf = *(const uint4*)&Vs[cur][n * 16 + (l & 15)][(l >> 4) << 3];
      const bf16x8 vb = __builtin_bit_cast(bf16x8, vf);
      acc[0][n] = __builtin_amdgcn_mfma_f32_16x16x32_bf16(pf0, vb, acc[0][n], 0, 0, 0);
      acc[1][n] = __builtin_amdgcn_mfma_f32_16x16x32_bf16(pf1, vb, acc[1][n], 0, 0, 0);
    }
    __builtin_amdgcn_s_setprio(0);
    if (++j == 16) break;
    wrV(cur ^ 1);
    __syncthreads();
    cur ^= 1;
  }
  // epilogue: partial denominators + unnormalized partial O (bf16)
  #pragma unroll
  for (int qs = 0; qs < 2; ++qs) {
    f32x4 dsum;
    #pragma unroll
    for (int r = 0; r < 4; ++r) {
      float s = lacc[qs][r];
      s += __shfl_xor(s, 1); s += __shfl_xor(s, 2);
      s += __shfl_xor(s, 4); s += __shfl_xor(s, 8);
      dsum[r] = s;
    }
    const int row = bh * 1024 + qr0 + qs * 16 + ((l >> 4) << 2);
    if ((l & 15) == 0) {
      #pragma unroll
      for (int r = 0; r < 4; ++r) pD[half * 32768 + row + r] = dsum[r];
    }
    __bf16* op = pO + (size_t)half * 8388608 + (size_t)row * 256 + (l & 15);
    #pragma unroll
    for (int n = 0; n < 16; ++n)
      #pragma unroll
      for (int r = 0; r < 4; ++r)
        op[(size_t)r * 256 + n * 16] = (__bf16)(acc[qs][n][r]);
  }
}

// ---------------- merge: ao = (P0+P1) / (16*(d0+d1)) ----------------------
__global__ __launch_bounds__(256) void attn_merge(
    const __bf16* __restrict__ pO, const float* __restrict__ pD,
    __bf16* __restrict__ ao)
{
  const int idx = blockIdx.x * 256 + threadIdx.x;   // 32768*32
  const int row = idx >> 5, e0 = (idx & 31) << 3;
  const float inv = __frcp_rn(16.f * (pD[row] + pD[32768 + row]));
  const bf16x8 a = *(const bf16x8*)(pO + (size_t)row * 256 + e0);
  const bf16x8 b = *(const bf16x8*)(pO + 8388608 + (size_t)row * 256 + e0);
  bf16x8 o;
  #pragma unroll
  for (int j = 0; j < 8; ++j) o[j] = (__bf16)(((float)a[j] + (float)b[j]) * inv);
  *(bf16x8*)(ao + (size_t)row * 256 + e0) = o;
}

// ---------------- host launch ----------------
extern "C" void kernel_launch(void* const* d_in, const int* in_sizes, int n_in,
                              void* d_out, int out_size, void* d_ws, size_t ws_size,
                              hipStream_t stream)
{
  const float* x    = (const float*)d_in[0];
  const float* ln1w = (const float*)d_in[1];
  const float* ln1b = (const float*)d_in[2];
  const float* Wq   = (const float*)d_in[3];
  const float* bq   = (const float*)d_in[4];
  const float* Wk   = (const float*)d_in[5];
  const float* bk   = (const float*)d_in[6];
  const float* Wv   = (const float*)d_in[7];
  const float* bv   = (const float*)d_in[8];
  const float* Wp   = (const float*)d_in[9];
  const float* bp   = (const float*)d_in[10];
  const float* ln2w = (const float*)d_in[11];
  const float* ln2b = (const float*)d_in[12];
  const float* W1   = (const float*)d_in[13];
  const float* b1   = (const float*)d_in[14];
  const float* W2   = (const float*)d_in[15];
  const float* b2   = (const float*)d_in[16];

  // ws layout (bytes), peak 136.3 MB:
  char* ws = (char*)d_ws;
  __bf16* wb   = (__bf16*)(ws);               // packed bf16 weights (1.5 MB)
  float*  bqkv = (float*)(ws + 1572864);      // packed qkv bias (3 KB)
  __bf16* y    = (__bf16*)(ws + 2097152);     // LN1 out / attn out (16 MB)
  __bf16* qkv  = (__bf16*)(ws + 18874368);    // packed QKV [M][768] (48 MB)
  float*  x1   = (float*)(ws + 18874368);     // residual fp32 (32 MB, aliases qkv lo)
  __bf16* hb   = (__bf16*)(ws + 52428800);    // LN2 out (16 MB, aliases qkv hi)
  __bf16* h1   = (__bf16*)(ws + 69206016);    // MLP hidden (64 MB)
  __bf16* pO   = (__bf16*)(ws + 69206016);    // partial O [2][32768][256] (33.5 MB, aliases h1)
  float*  pD   = (float*)(ws + 102760448);    // partial denom [2][32768] (256 KB)
  __bf16* ao   = y;
  float*  outp = (float*)d_out;

  packw<<<384, 256, 0, stream>>>(Wq, Wk, Wv, Wp, W1, W2, wb);
  packb<<<1, 768, 0, stream>>>(bq, bk, bv, bqkv);
  ln_rows<<<8192, 256, 0, stream>>>(x, ln1w, ln1b, y);
  // QKV: [32768][256] @ [768][256]^T -> [32768][768]
  bgemm<128, 3, 1, 0, 0, 1><<<768,  512, 0, stream>>>(y,  wb,          bqkv, nullptr, qkv,  768);
  attn_split<<<256, 512, 0, stream>>>(qkv, pO, pD);
  attn_merge<<<4096, 256, 0, stream>>>(pO, pD, ao);
  // proj: BM=64 -> grid 512 (2 blocks/CU), +x residual, fp32 out
  bgemm<64, 1, 1, 0, 1, 0><<<512,  512, 0, stream>>>(ao, wb + 196608, bp,   x,       x1,   256);
  ln_rows<<<8192, 256, 0, stream>>>(x1, ln2w, ln2b, hb);
  // MLP1: mish, bf16 out [32768][1024]
  bgemm<128, 4, 1, 1, 0, 1><<<1024, 512, 0, stream>>>(hb, wb + 262144, b1,  nullptr, h1,  1024);
  // MLP2: K=1024, BM=64 -> grid 512 (2 blocks/CU), mish + x1 residual, fp32 out
  bgemm<64, 1, 4, 1, 1, 0><<<512,  512, 0, stream>>>(h1, wb + 524288, b2,   x1,      outp, 256);
}

// Round 16
// 203.934 us; speedup vs baseline: 1.0769x; 1.0769x over previous
//
#include <hip/hip_runtime.h>

typedef float  f32x4  __attribute__((ext_vector_type(4)));
typedef float  f4v    __attribute__((ext_vector_type(4)));
typedef __bf16 bf16x8 __attribute__((ext_vector_type(8)));
typedef __bf16 bf16x4 __attribute__((ext_vector_type(4)));
typedef unsigned short ushort_t;

#define AS1 __attribute__((address_space(1)))
#define AS3 __attribute__((address_space(3)))

static __device__ __forceinline__ void gload_lds16(const void* g, void* l) {
  __builtin_amdgcn_global_load_lds((const AS1 void*)g, (AS3 void*)l, 16, 0, 0);
}

// mish(x) = x * u/(u+2), u = t*(t+2), t = e^x; guard large x.
static __device__ __forceinline__ float mishf(float x) {
  float t = __expf(x);
  float u = t * (t + 2.f);
  float y = x * __fdividef(u, u + 2.f);
  return (x > 15.f) ? x : y;
}

// ---------------- weight pack: fp32 -> bf16 in MFMA-fragment order --------
// idx = ((((cb*KC + c)*8 + u)*2 + n)*64 + l)*8 holds
// W[cb*32 + n*16 + (l&15)][c*256 + u*32 + (l>>4)*8 .. +8].
__global__ __launch_bounds__(256) void packw(
    const float* __restrict__ Wq, const float* __restrict__ Wk,
    const float* __restrict__ Wv, const float* __restrict__ Wp,
    const float* __restrict__ W1, const float* __restrict__ W2,
    __bf16* __restrict__ out)
{
  const int t = blockIdx.x * 256 + threadIdx.x;   // 98304 threads
  const int e0 = t * 8;
  int rel, K; const float* src;
  if      (e0 < 196608) { rel = e0;          K = 256;  src = nullptr; }
  else if (e0 < 262144) { rel = e0 - 196608; K = 256;  src = Wp; }
  else if (e0 < 524288) { rel = e0 - 262144; K = 256;  src = W1; }
  else                  { rel = e0 - 524288; K = 1024; src = W2; }
  const int percb = (K >> 8) * 8192;
  const int cb = rel / percb;  const int r1 = rel % percb;
  const int c  = r1 / 8192;    const int r2 = r1 % 8192;
  const int u  = r2 / 1024;    const int r3 = r2 % 1024;
  const int n  = r3 / 512;     const int l  = (r3 % 512) >> 3;
  const int col = cb * 32 + n * 16 + (l & 15);
  const int k   = c * 256 + u * 32 + ((l >> 4) << 3);
  const float* sp;
  if (e0 < 196608) {
    const float* qkvsrc = (col < 256) ? Wq : (col < 512 ? Wk : Wv);
    sp = qkvsrc + (size_t)(col & 255) * 256 + k;
  } else {
    sp = src + (size_t)col * K + k;
  }
  const f4v a = *(const f4v*)(sp);
  const f4v b = *(const f4v*)(sp + 4);
  bf16x8 o;
  #pragma unroll
  for (int j = 0; j < 4; ++j) { o[j] = (__bf16)a[j]; o[4 + j] = (__bf16)b[j]; }
  *(bf16x8*)(out + e0) = o;
}

__global__ void packb(const float* __restrict__ a, const float* __restrict__ b,
                      const float* __restrict__ c, float* __restrict__ o) {
  int i = threadIdx.x;  // 768 threads
  o[i] = (i < 256) ? a[i] : (i < 512 ? b[i - 256] : c[i - 512]);
}

// ---------------- LayerNorm row kernel: fp32 in -> bf16 out ----------------
__global__ __launch_bounds__(256) void ln_rows(
    const float* __restrict__ X, const float* __restrict__ g,
    const float* __restrict__ b, __bf16* __restrict__ Y)
{
  const int l = threadIdx.x & 63;
  const size_t row = (size_t)blockIdx.x * 4 + (threadIdx.x >> 6);
  const f4v x = *(const f4v*)(X + row * 256 + l * 4);
  float s = x[0] + x[1] + x[2] + x[3];
  float q = x[0]*x[0] + x[1]*x[1] + x[2]*x[2] + x[3]*x[3];
  #pragma unroll
  for (int d = 1; d < 64; d <<= 1) { s += __shfl_xor(s, d); q += __shfl_xor(q, d); }
  const float mu = s * (1.f / 256.f);
  const float rs = rsqrtf(q * (1.f / 256.f) - mu * mu + 1e-5f);
  const f4v gv = *(const f4v*)(g + l * 4);
  const f4v bv = *(const f4v*)(b + l * 4);
  bf16x4 o;
  #pragma unroll
  for (int j = 0; j < 4; ++j) o[j] = (__bf16)((x[j] - mu) * rs * gv[j] + bv[j]);
  *(bf16x4*)(Y + row * 256 + l * 4) = o;
}

// ---------------- B-streamed GEMM (occupancy-first, K<=1024) --------------
// out[M=32768][ldo](+nt*256) = act(A @ W^T + bias) (+res). K = KC*256.
// Block 512 thr / 8 waves; tile BM x 256; wave owns BM x 32. B fragments
// STREAMED per-u from the packed layout (2 live regs instead of 16).
// A staged in LDS (XOR-swizzled, conflict-free ds_read_b128).
template<int BM, int NT, int KC, int ACT, int RES, int OUTBF>
__global__ __launch_bounds__(512, 2) void bgemm(
    const __bf16* __restrict__ A, const __bf16* __restrict__ Wg,
    const float* __restrict__ bias, const float* __restrict__ res,
    void* __restrict__ out, int ldo)
{
  constexpr int K  = KC * 256;
  constexpr int MR = BM / 16;              // m-frags per wave
  __shared__ __bf16 Ab[BM * 256];
  const int tid = threadIdx.x, l = tid & 63, w = tid >> 6;
  constexpr int nwg = (32768 / BM) * NT;
  const int wg = (blockIdx.x & 7) * (nwg / 8) + (blockIdx.x >> 3);
  const int mt = wg / NT, nt = wg % NT;
  const int row0 = mt * BM;
  const int col0 = nt * 256 + w * 32;
  const int cb = nt * 8 + w;               // global 32-col block index

  auto stageA = [&](int c) {
    #pragma unroll
    for (int j = 0; j < BM / 16; ++j) {
      const int s = j * 512 + tid;         // 16B unit index
      const int r = s >> 5, q = s & 31;
      gload_lds16(A + (size_t)(row0 + r) * K + c * 256 + ((q ^ (r & 7)) << 3),
                  &Ab[s << 3]);
    }
  };

  auto ldBu = [&](bf16x8* d, int c, int u) {
    const __bf16* wp = Wg + (size_t)(cb * KC + c) * 8192 + (((u << 1) * 64 + l) << 3);
    d[0] = *(const bf16x8*)(wp);
    d[1] = *(const bf16x8*)(wp + 512);
  };

  f32x4 acc[MR][2] = {};

  stageA(0);
  asm volatile("s_waitcnt vmcnt(0)" ::: "memory");
  __builtin_amdgcn_s_barrier();

  for (int c = 0;;) {
    bf16x8 b0[2], b1[2];
    ldBu(b0, c, 0);
    #pragma unroll
    for (int u = 0; u < 8; ++u) {
      if (u + 1 < 8) ldBu((u & 1) ? b0 : b1, c, u + 1);
      const bf16x8* bu = (u & 1) ? b1 : b0;
      bf16x8 af[MR];
      #pragma unroll
      for (int m = 0; m < MR; ++m) {
        const int r = m * 16 + (l & 15);
        const int q = ((u << 2) | (l >> 4)) ^ (r & 7);
        af[m] = *(const bf16x8*)&Ab[((r << 5) | q) << 3];
      }
      #pragma unroll
      for (int m = 0; m < MR; ++m) {
        acc[m][0] = __builtin_amdgcn_mfma_f32_16x16x32_bf16(af[m], bu[0], acc[m][0], 0, 0, 0);
        acc[m][1] = __builtin_amdgcn_mfma_f32_16x16x32_bf16(af[m], bu[1], acc[m][1], 0, 0, 0);
      }
    }
    if (++c == KC) break;
    __syncthreads();           // all waves done reading Ab
    stageA(c);
    asm volatile("s_waitcnt vmcnt(0)" ::: "memory");
    __builtin_amdgcn_s_barrier();
  }

  // epilogue: row-contiguous direct stores
  const float b0s = bias[col0 + (l & 15)];
  const float b1s = bias[col0 + 16 + (l & 15)];
  #pragma unroll
  for (int m = 0; m < MR; ++m) {
    #pragma unroll
    for (int r = 0; r < 4; ++r) {
      const int row = row0 + m * 16 + ((l >> 4) << 2) + r;
      float v0 = acc[m][0][r] + b0s;
      float v1 = acc[m][1][r] + b1s;
      if (ACT) { v0 = mishf(v0); v1 = mishf(v1); }
      if (OUTBF) {
        __bf16* op = (__bf16*)out + (size_t)row * ldo + col0;
        op[l & 15]        = (__bf16)v0;
        op[16 + (l & 15)] = (__bf16)v1;
      } else {
        if (RES) {
          const float* rp = res + (size_t)row * ldo + col0;
          v0 += rp[l & 15];
          v1 += rp[16 + (l & 15)];
        }
        float* op = (float*)out + (size_t)row * ldo + col0;
        op[l & 15]        = v0;
        op[16 + (l & 15)] = v1;
      }
    }
  }
}

// ---------------- flash attention over packed QKV [M][768] ----------------
// R9 structure (proven 75.5 us) + bank-conflict fixes: Vs and Ps accessed
// through bijective 16B-unit XOR swizzles (both sides swizzled):
//   Vs: u ^= (row&3) ^ ((row>>3)&3)  -> V-transpose stores conflict-free,
//       PV b128 reads 2-way (free).
//   Ps: u ^= (row&3) ^ ((row>>2)&3)  -> b128 reads conflict-free (banks
//       {0,20,8,28,4,16,12,24}), scalar writes <=2-way.
__global__ __launch_bounds__(512) void attn_fwd(
    const __bf16* __restrict__ QKV, __bf16* __restrict__ Om)
{
  __shared__ __bf16 Ks[2][32][256];   // 32 KB, XOR-swizzled rows
  __shared__ __bf16 Vs[2][256 * 32];  // 32 KB, V^T [e][kv], unit-swizzled
  __shared__ __bf16 Ps[8][16 * 32];   // 8 KB, per-wave P, unit-swizzled
  const int tid = threadIdx.x, l = tid & 63, w = tid >> 6;
  const int wgs = (blockIdx.x & 7) * 32 + (blockIdx.x >> 3);
  const int bh = wgs >> 3, qt = wgs & 7;
  const size_t rbase = (size_t)bh * 1024 * 768;   // bh row base in QKV
  const int qr0 = qt * 128 + w * 16;

  bf16x8 qf[8];
  {
    const __bf16* qp = QKV + rbase + (size_t)(qr0 + (l & 15)) * 768 + ((l >> 4) << 3);
    #pragma unroll
    for (int s = 0; s < 8; ++s) qf[s] = *(const bf16x8*)(qp + s * 32);
  }
  f32x4 acc[16] = {};
  float lacc[4] = {0.f, 0.f, 0.f, 0.f};

  const int kec = tid & 31, kr_ = tid >> 5;
  const int vp = tid & 15, vc = tid >> 4;
  const __bf16* gK = QKV + 256 + rbase + kec * 8;
  const __bf16* gV = QKV + 512 + rbase + vc * 8;

  uint4 rk0, rk1, rv0, rv1;
  auto ldKV = [&](int kt) {
    const __bf16* k0 = gK + (size_t)(kt * 32 + kr_) * 768;
    rk0 = *(const uint4*)k0;
    rk1 = *(const uint4*)(k0 + 16 * 768);
    const __bf16* v0 = gV + (size_t)(kt * 32 + vp * 2) * 768;
    rv0 = *(const uint4*)v0;
    rv1 = *(const uint4*)(v0 + 768);
  };
  auto wrKV = [&](int buf) {
    char* kb = (char*)&Ks[buf][0][0];
    const int a0 = (kr_ * 512 + kec * 16) ^ ((kr_ & 15) << 4);
    const int a1 = ((kr_ + 16) * 512 + kec * 16) ^ (((kr_ + 16) & 15) << 4);
    *(uint4*)(kb + a0) = rk0;
    *(uint4*)(kb + a1) = rk1;
    char* vb = (char*)&Vs[buf][0];
    const ushort_t* s0 = (const ushort_t*)&rv0;
    const ushort_t* s1 = (const ushort_t*)&rv1;
    const int u = vp >> 2, ub = (vp & 3) * 4;
    #pragma unroll
    for (int i = 0; i < 8; ++i) {
      unsigned pk = (unsigned)s0[i] | ((unsigned)s1[i] << 16);
      const int row = vc * 8 + i;
      const int swz = u ^ (row & 3) ^ ((row >> 3) & 3);
      *(unsigned*)(vb + row * 64 + (swz << 4) + ub) = pk;
    }
  };

  ldKV(0); wrKV(0);
  __syncthreads();
  int cur = 0;
  for (int kt = 0;;) {
    if (kt + 1 < 32) ldKV(kt + 1);
    f32x4 S[2] = {};
    const char* kbase = (const char*)&Ks[cur][0][0];
    #pragma unroll
    for (int t = 0; t < 2; ++t) {
      const int kcol = t * 16 + (l & 15);
      const int swz = (kcol & 15) << 4;
      #pragma unroll
      for (int s = 0; s < 8; ++s) {
        uint4 kf = *(const uint4*)(kbase + ((kcol * 512 + s * 64 + ((l >> 4) << 4)) ^ swz));
        S[t] = __builtin_amdgcn_mfma_f32_16x16x32_bf16(qf[s], __builtin_bit_cast(bf16x8, kf), S[t], 0, 0, 0);
      }
    }
    char* pb = (char*)&Ps[w][0];
    #pragma unroll
    for (int t = 0; t < 2; ++t)
      #pragma unroll
      for (int r = 0; r < 4; ++r) {
        float p = __expf(S[t][r]);
        lacc[r] += p;
        const int qr = ((l >> 4) << 2) + r;
        const int c = t * 16 + (l & 15);
        const int swz = (c >> 3) ^ (qr & 3) ^ ((qr >> 2) & 3);
        *(__bf16*)(pb + qr * 64 + (swz << 4) + ((c & 7) * 2)) = (__bf16)p;
      }
    const int prow = l & 15;
    const int pswz = (l >> 4) ^ (prow & 3) ^ ((prow >> 2) & 3);
    bf16x8 pf = *(const bf16x8*)(pb + prow * 64 + (pswz << 4));
    const char* vb = (const char*)&Vs[cur][0];
    #pragma unroll
    for (int n = 0; n < 16; ++n) {
      const int row = n * 16 + (l & 15);
      const int swz = (l >> 4) ^ (row & 3) ^ ((row >> 3) & 3);
      uint4 vf = *(const uint4*)(vb + row * 64 + (swz << 4));
      acc[n] = __builtin_amdgcn_mfma_f32_16x16x32_bf16(pf, __builtin_bit_cast(bf16x8, vf), acc[n], 0, 0, 0);
    }
    if (++kt == 32) break;
    wrKV(cur ^ 1);
    __syncthreads();
    cur ^= 1;
  }
  f32x4 inv;
  #pragma unroll
  for (int r = 0; r < 4; ++r) {
    float s = lacc[r];
    s += __shfl_xor(s, 1); s += __shfl_xor(s, 2);
    s += __shfl_xor(s, 4); s += __shfl_xor(s, 8);
    inv[r] = 1.f / (16.f * s);
  }
  __bf16* op = Om + (size_t)(bh * 1024 + qr0 + ((l >> 4) << 2)) * 256 + (l & 15);
  #pragma unroll
  for (int n = 0; n < 16; ++n)
    #pragma unroll
    for (int r = 0; r < 4; ++r)
      op[(size_t)r * 256 + n * 16] = (__bf16)(acc[n][r] * inv[r]);
}

// ---------------- host launch ----------------
extern "C" void kernel_launch(void* const* d_in, const int* in_sizes, int n_in,
                              void* d_out, int out_size, void* d_ws, size_t ws_size,
                              hipStream_t stream)
{
  const float* x    = (const float*)d_in[0];
  const float* ln1w = (const float*)d_in[1];
  const float* ln1b = (const float*)d_in[2];
  const float* Wq   = (const float*)d_in[3];
  const float* bq   = (const float*)d_in[4];
  const float* Wk   = (const float*)d_in[5];
  const float* bk   = (const float*)d_in[6];
  const float* Wv   = (const float*)d_in[7];
  const float* bv   = (const float*)d_in[8];
  const float* Wp   = (const float*)d_in[9];
  const float* bp   = (const float*)d_in[10];
  const float* ln2w = (const float*)d_in[11];
  const float* ln2b = (const float*)d_in[12];
  const float* W1   = (const float*)d_in[13];
  const float* b1   = (const float*)d_in[14];
  const float* W2   = (const float*)d_in[15];
  const float* b2   = (const float*)d_in[16];

  // ws layout (bytes), peak 136.3 MB:
  char* ws = (char*)d_ws;
  __bf16* wb   = (__bf16*)(ws);               // packed bf16 weights (1.5 MB)
  float*  bqkv = (float*)(ws + 1572864);      // packed qkv bias (3 KB)
  __bf16* y    = (__bf16*)(ws + 2097152);     // LN1 out / attn out (16 MB)
  __bf16* qkv  = (__bf16*)(ws + 18874368);    // packed QKV [M][768] (48 MB)
  float*  x1   = (float*)(ws + 18874368);     // residual fp32 (32 MB, aliases qkv lo)
  __bf16* hb   = (__bf16*)(ws + 52428800);    // LN2 out (16 MB, aliases qkv hi)
  __bf16* h1   = (__bf16*)(ws + 69206016);    // MLP hidden (64 MB)
  __bf16* ao   = y;
  float*  outp = (float*)d_out;

  packw<<<384, 256, 0, stream>>>(Wq, Wk, Wv, Wp, W1, W2, wb);
  packb<<<1, 768, 0, stream>>>(bq, bk, bv, bqkv);
  ln_rows<<<8192, 256, 0, stream>>>(x, ln1w, ln1b, y);
  // QKV: [32768][256] @ [768][256]^T -> [32768][768]
  bgemm<128, 3, 1, 0, 0, 1><<<768,  512, 0, stream>>>(y,  wb,          bqkv, nullptr, qkv,  768);
  attn_fwd<<<256, 512, 0, stream>>>(qkv, ao);
  // proj: BM=64 -> grid 512 (2 blocks/CU), +x residual, fp32 out
  bgemm<64, 1, 1, 0, 1, 0><<<512,  512, 0, stream>>>(ao, wb + 196608, bp,   x,       x1,   256);
  ln_rows<<<8192, 256, 0, stream>>>(x1, ln2w, ln2b, hb);
  // MLP1: mish, bf16 out [32768][1024]
  bgemm<128, 4, 1, 1, 0, 1><<<1024, 512, 0, stream>>>(hb, wb + 262144, b1,  nullptr, h1,  1024);
  // MLP2: K=1024, BM=64 -> grid 512 (2 blocks/CU), mish + x1 residual, fp32 out
  bgemm<64, 1, 4, 1, 1, 0><<<512,  512, 0, stream>>>(h1, wb + 524288, b2,   x1,      outp, 256);
}